// Round 1
// baseline (77.737 us; speedup 1.0000x reference)
//
#include <hip/hip_runtime.h>
#include <math.h>

#define GMM_D 32
#define GMM_K 16

// out[n][k] = alpha_k - LSE(alpha) - sum_d log(std_kd) - (D/2)*log(2*pi)
//             - 0.5 * sum_d min( ((x_nd - mu_kd)/std_kd)^2 , 20 )
// with std = max(std, 0.1).  min(z^2,20) == the reference's
// max(-0.5*dist, -10) pulled through the -0.5 factor (monotone, exact).

__global__ __launch_bounds__(256) void gmm_kernel(
    const float* __restrict__ x,
    const float* __restrict__ mu,
    const float* __restrict__ stdv,
    const float* __restrict__ alpha,
    float* __restrict__ out, int N)
{
    // (inv_std, -mu*inv_std) for dim pairs -> ds_read_b128 broadcast in hot loop
    __shared__ float4 cpair[GMM_K * GMM_D / 2];
    __shared__ float ck[GMM_K];
    __shared__ float lsums[GMM_K * GMM_D];

    const int tid = threadIdx.x;

    // ---- per-block constant setup (tiny: 512 entries) ----
    for (int i = tid; i < GMM_K * GMM_D / 2; i += 256) {
        const int e0 = 2 * i, e1 = 2 * i + 1;
        const float s0 = fmaxf(stdv[e0], 0.1f);
        const float s1 = fmaxf(stdv[e1], 0.1f);
        const float is0 = 1.0f / s0;
        const float is1 = 1.0f / s1;
        cpair[i] = make_float4(is0, -mu[e0] * is0, is1, -mu[e1] * is1);
        lsums[e0] = logf(s0);
        lsums[e1] = logf(s1);
    }
    __syncthreads();
    if (tid < GMM_K) {
        // log-softmax constant per component (redundant across 16 lanes, trivial)
        float m = alpha[0];
        for (int k = 1; k < GMM_K; ++k) m = fmaxf(m, alpha[k]);
        float se = 0.0f;
        for (int k = 0; k < GMM_K; ++k) se += expf(alpha[k] - m);
        const float lse = m + logf(se);
        float s = 0.0f;
        for (int d = 0; d < GMM_D; ++d) s += lsums[tid * GMM_D + d];
        // (D/2)*log(2*pi) = 16 * 1.8378770664093453 = 29.406033062549525
        ck[tid] = alpha[tid] - lse - s - 29.406033062549525f;
    }
    __syncthreads();

    const int n = blockIdx.x * 256 + tid;
    if (n >= N) return;

    // ---- load this point's 32 dims into registers (8x float4) ----
    float xr[GMM_D];
    const float4* xv = reinterpret_cast<const float4*>(x + (size_t)n * GMM_D);
#pragma unroll
    for (int i = 0; i < GMM_D / 4; ++i) {
        const float4 v = xv[i];
        xr[4 * i + 0] = v.x; xr[4 * i + 1] = v.y;
        xr[4 * i + 2] = v.z; xr[4 * i + 3] = v.w;
    }

    float4* ov = reinterpret_cast<float4*>(out + (size_t)n * GMM_K);
    // 4 components per iteration: 4 independent acc chains (ILP), float4 store.
    for (int kq = 0; kq < GMM_K / 4; ++kq) {
        float a0 = 0.f, a1 = 0.f, a2 = 0.f, a3 = 0.f;
        const int b0 = (4 * kq + 0) * (GMM_D / 2);
        const int b1 = (4 * kq + 1) * (GMM_D / 2);
        const int b2 = (4 * kq + 2) * (GMM_D / 2);
        const int b3 = (4 * kq + 3) * (GMM_D / 2);
#pragma unroll
        for (int h = 0; h < GMM_D / 2; ++h) {
            const float4 c0 = cpair[b0 + h];
            const float4 c1 = cpair[b1 + h];
            const float4 c2 = cpair[b2 + h];
            const float4 c3 = cpair[b3 + h];
            const float x0 = xr[2 * h], x1 = xr[2 * h + 1];
            float z;
            z = fmaf(x0, c0.x, c0.y); a0 += fminf(z * z, 20.0f);
            z = fmaf(x1, c0.z, c0.w); a0 += fminf(z * z, 20.0f);
            z = fmaf(x0, c1.x, c1.y); a1 += fminf(z * z, 20.0f);
            z = fmaf(x1, c1.z, c1.w); a1 += fminf(z * z, 20.0f);
            z = fmaf(x0, c2.x, c2.y); a2 += fminf(z * z, 20.0f);
            z = fmaf(x1, c2.z, c2.w); a2 += fminf(z * z, 20.0f);
            z = fmaf(x0, c3.x, c3.y); a3 += fminf(z * z, 20.0f);
            z = fmaf(x1, c3.z, c3.w); a3 += fminf(z * z, 20.0f);
        }
        float4 r;
        r.x = ck[4 * kq + 0] - 0.5f * a0;
        r.y = ck[4 * kq + 1] - 0.5f * a1;
        r.z = ck[4 * kq + 2] - 0.5f * a2;
        r.w = ck[4 * kq + 3] - 0.5f * a3;
        ov[kq] = r;
    }
}

extern "C" void kernel_launch(void* const* d_in, const int* in_sizes, int n_in,
                              void* d_out, int out_size, void* d_ws, size_t ws_size,
                              hipStream_t stream) {
    const float* x     = (const float*)d_in[0];
    const float* mu    = (const float*)d_in[1];
    const float* stdv  = (const float*)d_in[2];
    const float* alpha = (const float*)d_in[3];
    float* out = (float*)d_out;

    const int N = in_sizes[0] / GMM_D;       // 131072
    const int grid = (N + 255) / 256;        // 512 blocks
    gmm_kernel<<<grid, 256, 0, stream>>>(x, mu, stdv, alpha, out, N);
}